// Round 13
// baseline (136.726 us; speedup 1.0000x reference)
//
#include <hip/hip_runtime.h>
#include <math.h>

#define NN 10000
#define NE 160000
#define NROWT 79              // ceil(NN/128)
#define NCOLT 16              // 2048 cols / 128
#define NGEMM (NROWT * NCOLT)

typedef __attribute__((ext_vector_type(8))) short bf16x8;
typedef __attribute__((ext_vector_type(4))) float f32x4;
typedef __attribute__((ext_vector_type(2))) float f32x2;

#if defined(__has_builtin)
#if __has_builtin(__builtin_amdgcn_cvt_pk_fp8_f32) && __has_builtin(__builtin_amdgcn_cvt_pk_f32_fp8)
#define HW_FP8 1
#endif
#endif

__device__ inline ushort f2bf(float x) {
  uint u = __float_as_uint(x);
  return (ushort)((u + 0x7fffu + ((u >> 16) & 1u)) >> 16);
}
__device__ inline uint pk2bf(float a, float b) {
  return (uint)f2bf(a) | ((uint)f2bf(b) << 16);
}

__device__ inline void unpack8(uint4 u, float* f) {
  f[0] = __uint_as_float(u.x << 16); f[1] = __uint_as_float(u.x & 0xffff0000u);
  f[2] = __uint_as_float(u.y << 16); f[3] = __uint_as_float(u.y & 0xffff0000u);
  f[4] = __uint_as_float(u.z << 16); f[5] = __uint_as_float(u.z & 0xffff0000u);
  f[6] = __uint_as_float(u.w << 16); f[7] = __uint_as_float(u.w & 0xffff0000u);
}

#ifndef HW_FP8
__device__ inline float fp8_dec1(uint b) {
  uint s = b >> 7, e = (b >> 3) & 15, m = b & 7;
  float v = (e == 0) ? ldexpf((float)m, -9) : ldexpf((float)(8 + m), (int)e - 10);
  return s ? -v : v;
}
__device__ inline uint fp8_enc1(float x) {
  uint s = (__float_as_uint(x) >> 31) << 7;
  float a = fabsf(x);
  if (!(a < 448.f)) return s | 0x7e;
  if (a < 9.765625e-4f) return s;
  int e; float m = frexpf(a, &e);
  int E = e - 1, q;
  if (E < -6) {
    q = (int)rintf(ldexpf(a, 9));
    if (q == 0) return s;
    if (q >= 8) return s | 8;
    return s | (uint)q;
  }
  q = (int)rintf(ldexpf(m, 4));
  if (q == 16) { q = 8; ++E; }
  if (E > 8 || (E == 8 && q == 15)) return s | 0x7e;
  return s | ((uint)(E + 7) << 3) | (uint)(q - 8);
}
#endif

__device__ inline uint pack4_fp8(float a, float b, float c, float d) {
#ifdef HW_FP8
  uint w = (uint)__builtin_amdgcn_cvt_pk_fp8_f32(a, b, 0, false);
  w = (uint)__builtin_amdgcn_cvt_pk_fp8_f32(c, d, (int)w, true);
  return w;
#else
  return fp8_enc1(a) | (fp8_enc1(b) << 8) | (fp8_enc1(c) << 16) | (fp8_enc1(d) << 24);
#endif
}

__device__ inline void dec8_fp8(uint lo, uint hi, float* f) {
#ifdef HW_FP8
  f32x2 p0 = __builtin_amdgcn_cvt_pk_f32_fp8((int)lo, false);
  f32x2 p1 = __builtin_amdgcn_cvt_pk_f32_fp8((int)lo, true);
  f32x2 p2 = __builtin_amdgcn_cvt_pk_f32_fp8((int)hi, false);
  f32x2 p3 = __builtin_amdgcn_cvt_pk_f32_fp8((int)hi, true);
  f[0] = p0.x; f[1] = p0.y; f[2] = p1.x; f[3] = p1.y;
  f[4] = p2.x; f[5] = p2.y; f[6] = p3.x; f[7] = p3.y;
#else
  f[0] = fp8_dec1(lo & 255); f[1] = fp8_dec1((lo >> 8) & 255);
  f[2] = fp8_dec1((lo >> 16) & 255); f[3] = fp8_dec1(lo >> 24);
  f[4] = fp8_dec1(hi & 255); f[5] = fp8_dec1((hi >> 8) & 255);
  f[6] = fp8_dec1((hi >> 16) & 255); f[7] = fp8_dec1(hi >> 24);
#endif
}

__device__ inline void dec16(uint4 u, float* f) {
  dec8_fp8(u.x, u.y, f);
  dec8_fp8(u.z, u.w, f + 8);
}

// ---- K0: zero deg + d_out ---------------------------------------------------
__global__ __launch_bounds__(1024) void zero_k(
    int* __restrict__ deg, float* __restrict__ out)
{
  int i = blockIdx.x * 1024 + threadIdx.x;
  if (i < NN) deg[i] = 0;
  if (i == 0) out[0] = 0.f;
}

// ---- K1: degree count (global atomics) + fp32->bf16 conversions ------------
__global__ __launch_bounds__(256) void prep_k(
    const float* __restrict__ x,
    const float* __restrict__ Wq1, const float* __restrict__ Wk1,
    const float* __restrict__ Wv1, const float* __restrict__ Ws1,
    ushort* __restrict__ x_bf, ushort* __restrict__ w1bf,
    const int* __restrict__ dst, int* __restrict__ deg)
{
  int i = blockIdx.x * 256 + threadIdx.x;
  if (i < NE) atomicAdd(&deg[dst[i]], 1);
  const int n4x = NN * 32;
  const int n4w = 512 * 128 / 4;
  if (i < n4x) {
    float4 v = ((const float4*)x)[i];
    ushort4 o;
    o.x = f2bf(v.x); o.y = f2bf(v.y); o.z = f2bf(v.z); o.w = f2bf(v.w);
    ((ushort4*)x_bf)[i] = o;
  } else {
    int c = i - n4x;
    if (c < 4 * n4w) {
      int seg = c >> 14, k = c & 16383;
      const float* W = (seg == 0) ? Wq1 : (seg == 1) ? Wk1
                     : (seg == 2) ? Wv1 : Ws1;
      float4 v = ((const float4*)W)[k];
      ushort4 o;
      o.x = f2bf(v.x); o.y = f2bf(v.y); o.z = f2bf(v.z); o.w = f2bf(v.w);
      ((ushort4*)(w1bf + ((size_t)seg << 16)))[k] = o;
    }
  }
}

// ---- K2: CSR scan (shfl-based) ----------------------------------------------
__global__ __launch_bounds__(1024) void scan_k(
    const int* __restrict__ deg, int* __restrict__ rowptr,
    int* __restrict__ cursor)
{
  __shared__ int wsum[16];
  int tid = threadIdx.x;
  int base = tid * 10;
  int loc[10]; int s = 0;
  #pragma unroll
  for (int i = 0; i < 10; ++i) {
    int v = (base + i < NN) ? deg[base + i] : 0;
    loc[i] = s; s += v;
  }
  int mysum = s;
  #pragma unroll
  for (int d = 1; d < 64; d <<= 1) {
    int v = __shfl_up(s, d);
    if ((tid & 63) >= d) s += v;
  }
  if ((tid & 63) == 63) wsum[tid >> 6] = s;
  __syncthreads();
  int woff = 0;
  for (int w = 0; w < (tid >> 6); ++w) woff += wsum[w];
  int excl = woff + s - mysum;
  #pragma unroll
  for (int i = 0; i < 10; ++i) {
    int idx = base + i;
    if (idx < NN) { int r = excl + loc[i]; rowptr[idx] = r; cursor[idx] = r; }
  }
  if (tid == 1023) rowptr[NN] = woff + s;
}

// ---- K3: layer-1 GEMM 128x128 tiles (bf16 MFMA, fp8 out) + scatter ---------
__global__ __launch_bounds__(256) void gemm_scatter(
    const ushort* __restrict__ xbf, const ushort* __restrict__ wbf,
    const float* __restrict__ bq, const float* __restrict__ bk,
    const float* __restrict__ bv, const float* __restrict__ bs,
    unsigned char* __restrict__ q8, unsigned char* __restrict__ kv8,
    ushort* __restrict__ h1b,
    const int* __restrict__ src, const int* __restrict__ dst,
    int* __restrict__ cursor, int* __restrict__ csr_src)
{
  if (blockIdx.x >= NGEMM) {   // ---- scatter part ----
    int e = (blockIdx.x - NGEMM) * 256 + threadIdx.x;
    if (e < NE) {
      int pos = atomicAdd(&cursor[dst[e]], 1);
      csr_src[pos] = src[e];
    }
    return;
  }
  __shared__ __align__(16) ushort LDSbuf[32768];   // 64 KB: Al 32K | Bl 32K
  ushort* Al = LDSbuf;             // [128][128] swizzled
  ushort* Bl = LDSbuf + 16384;
  const int row0 = (blockIdx.x % NROWT) << 7;
  const int ncol0 = (blockIdx.x / NROWT) << 7;   // 0..1920
  const int tid = threadIdx.x;

  #pragma unroll
  for (int i = 0; i < 8; ++i) {
    int slot = tid + (i << 8);
    int r = slot >> 4, c = slot & 15;
    int gr = row0 + r;
    uint4 v = make_uint4(0u, 0u, 0u, 0u);
    if (gr < NN) v = *(const uint4*)(xbf + (size_t)gr * 128 + (c << 3));
    *(uint4*)(Al + r * 128 + ((c ^ (r & 7)) << 3)) = v;
  }
  #pragma unroll
  for (int i = 0; i < 8; ++i) {
    int slot = tid + (i << 8);
    int r = slot >> 4, c = slot & 15;
    uint4 v = *(const uint4*)(wbf + (size_t)(ncol0 + r) * 128 + (c << 3));
    *(uint4*)(Bl + r * 128 + ((c ^ (r & 7)) << 3)) = v;
  }
  __syncthreads();

  const int wv = tid >> 6, lane = tid & 63;
  const int lr = lane & 15, lkg = lane >> 4;
  const int seg = ncol0 >> 9;
  const int colInSeg = ncol0 & 511;
  const bool swp = (seg < 3);         // q,k,v -> fp8, D^T layout

  f32x4 acc[2][8];
  #pragma unroll
  for (int m = 0; m < 2; ++m)
    #pragma unroll
    for (int n = 0; n < 8; ++n) acc[m][n] = (f32x4){0.f, 0.f, 0.f, 0.f};

  #pragma unroll
  for (int ks = 0; ks < 4; ++ks) {
    int c16 = (ks << 2) + lkg;
    bf16x8 a[2], b[8];
    #pragma unroll
    for (int mf = 0; mf < 2; ++mf) {
      int r = (wv << 5) + (mf << 4) + lr;
      a[mf] = *(const bf16x8*)(Al + r * 128 + ((c16 ^ (r & 7)) << 3));
    }
    #pragma unroll
    for (int nf = 0; nf < 8; ++nf) {
      int r = (nf << 4) + lr;
      b[nf] = *(const bf16x8*)(Bl + r * 128 + ((c16 ^ (r & 7)) << 3));
    }
    if (swp) {
      #pragma unroll
      for (int mf = 0; mf < 2; ++mf)
        #pragma unroll
        for (int nf = 0; nf < 8; ++nf)
          acc[mf][nf] = __builtin_amdgcn_mfma_f32_16x16x32_bf16(
              b[nf], a[mf], acc[mf][nf], 0, 0, 0);
    } else {
      #pragma unroll
      for (int mf = 0; mf < 2; ++mf)
        #pragma unroll
        for (int nf = 0; nf < 8; ++nf)
          acc[mf][nf] = __builtin_amdgcn_mfma_f32_16x16x32_bf16(
              a[mf], b[nf], acc[mf][nf], 0, 0, 0);
    }
  }

  // ---- epilogue: two 64-col passes through S [128][68] f32 -----------------
  __syncthreads();                      // done reading Al/Bl
  float* S = (float*)LDSbuf;            // 34816 B
  const float* bias = (seg == 0) ? bq : (seg == 1) ? bk : (seg == 2) ? bv : bs;

  if (swp) {
    const float scale = (seg == 0) ? 0.08838834764831845f : 1.f;
    unsigned char* out8 = (seg == 0) ? q8 : kv8;
    const int rs = (seg == 0) ? 512 : 1024;
    const int choff = ((seg == 2) ? 512 : 0) + colInSeg;
    #pragma unroll
    for (int pass = 0; pass < 2; ++pass) {
      #pragma unroll
      for (int mf = 0; mf < 2; ++mf) {
        int rl = (wv << 5) + (mf << 4) + lr;
        #pragma unroll
        for (int nf2 = 0; nf2 < 4; ++nf2) {
          int nf = (pass << 2) + nf2;
          int cl = (nf << 4) + (lkg << 2);          // 0..127
          float4 bb = *(const float4*)(bias + colInSeg + cl);
          float4 o;
          o.x = (acc[mf][nf][0] + bb.x) * scale;
          o.y = (acc[mf][nf][1] + bb.y) * scale;
          o.z = (acc[mf][nf][2] + bb.z) * scale;
          o.w = (acc[mf][nf][3] + bb.w) * scale;
          *(float4*)(S + rl * 68 + (cl - (pass << 6))) = o;
        }
      }
      __syncthreads();
      for (int tt = tid; tt < 512; tt += 256) {
        int row = tt >> 2, q4 = (tt & 3) << 4;
        int grow = row0 + row;
        if (grow < NN) {
          const float* p = S + row * 68 + q4;
          uint4 w;
          w.x = pack4_fp8(p[0],  p[1],  p[2],  p[3]);
          w.y = pack4_fp8(p[4],  p[5],  p[6],  p[7]);
          w.z = pack4_fp8(p[8],  p[9],  p[10], p[11]);
          w.w = pack4_fp8(p[12], p[13], p[14], p[15]);
          *(uint4*)(out8 + (size_t)grow * rs + choff + (pass << 6) + q4) = w;
        }
      }
      __syncthreads();
    }
  } else {
    #pragma unroll
    for (int pass = 0; pass < 2; ++pass) {
      #pragma unroll
      for (int mf = 0; mf < 2; ++mf) {
        #pragma unroll
        for (int nf2 = 0; nf2 < 4; ++nf2) {
          int nf = (pass << 2) + nf2;
          int cl = (nf << 4) + lr;
          float bb = bias[colInSeg + cl];
          #pragma unroll
          for (int r = 0; r < 4; ++r) {
            int rl = (wv << 5) + (mf << 4) + (lkg << 2) + r;
            S[rl * 68 + (cl - (pass << 6))] = acc[mf][nf][r] + bb;
          }
        }
      }
      __syncthreads();
      for (int tt = tid; tt < 1024; tt += 256) {
        int row = tt >> 3, g = tt & 7;
        int grow = row0 + row;
        if (grow < NN) {
          const float* p = S + row * 68 + (g << 3);
          uint4 w;
          w.x = pk2bf(p[0], p[1]);
          w.y = pk2bf(p[2], p[3]);
          w.z = pk2bf(p[4], p[5]);
          w.w = pk2bf(p[6], p[7]);
          *(uint4*)(h1b + (size_t)grow * 512 + colInSeg + (pass << 6) + (g << 3)) = w;
        }
      }
      __syncthreads();
    }
  }
}

// ---- K4: fused layer-1 attention + layer-2 projections ---------------------
// 4 nodes/block, 1 wave/node. Attention as before (k-lanes/v-lanes).
// Then h1 row -> 2KB LDS (per wave), all 64 lanes do the 16 512-dots
// straight from L1/L2-cached W2 (no staging, no h1b round-trip).
#define EDGE_A(kvreg)                                                      \
  {                                                                        \
    float f[16]; dec16(kvreg, f);                                          \
    float t = qf[0]*f[0]+qf[1]*f[1]+qf[2]*f[2]+qf[3]*f[3]                  \
            + qf[4]*f[4]+qf[5]*f[5]+qf[6]*f[6]+qf[7]*f[7]                  \
            + qf[8]*f[8]+qf[9]*f[9]+qf[10]*f[10]+qf[11]*f[11]              \
            + qf[12]*f[12]+qf[13]*f[13]+qf[14]*f[14]+qf[15]*f[15];         \
    t += __shfl_xor(t, 1);                                                 \
    t += __shfl_xor(t, 2);                                                 \
    t += __shfl_xor(t, 4);                                                 \
    float exA = __expf(t);                                                 \
    float exO = __shfl_xor(exA, 32);                                       \
    if (kl) den += exA;                                                    \
    float exV = kl ? 0.f : exO;                                            \
    _Pragma("unroll")                                                      \
    for (int i = 0; i < 16; ++i) acc[i] = fmaf(exV, f[i], acc[i]);         \
  }

__global__ __launch_bounds__(256) void attn_fused(
    const unsigned char* __restrict__ q8, const unsigned char* __restrict__ kv8,
    const int* __restrict__ rowptr, const int* __restrict__ csr_src,
    const ushort* __restrict__ h1b,
    const float* __restrict__ Wq2, const float* __restrict__ bq2,
    const float* __restrict__ Wk2, const float* __restrict__ bk2,
    const float* __restrict__ Wv2, const float* __restrict__ bv2,
    const float* __restrict__ Ws2, const float* __restrict__ bs2,
    float* __restrict__ qkv2, float* __restrict__ acc2)
{
  __shared__ float hl[4][512];
  const int ns = threadIdx.x >> 6;
  const int n = blockIdx.x * 4 + ns;
  const int lane = threadIdx.x & 63;
  const bool kl = lane < 32;
  const int vl = lane & 31;

  float qf[16];
  if (kl) {
    uint4 qv = *(const uint4*)(q8 + (size_t)n * 512 + (lane << 4));
    dec16(qv, qf);
  } else {
    #pragma unroll
    for (int i = 0; i < 16; ++i) qf[i] = 0.f;
  }

  float acc[16] = {};
  float den = 0.f;
  int j = rowptr[n];
  const int e1 = rowptr[n + 1];
  for (; j + 7 < e1; j += 8) {
    uint4 a0 = *(const uint4*)(kv8 + (size_t)csr_src[j + 0] * 1024 + (lane << 4));
    uint4 a1 = *(const uint4*)(kv8 + (size_t)csr_src[j + 1] * 1024 + (lane << 4));
    uint4 a2 = *(const uint4*)(kv8 + (size_t)csr_src[j + 2] * 1024 + (lane << 4));
    uint4 a3 = *(const uint4*)(kv8 + (size_t)csr_src[j + 3] * 1024 + (lane << 4));
    uint4 a4 = *(const uint4*)(kv8 + (size_t)csr_src[j + 4] * 1024 + (lane << 4));
    uint4 a5 = *(const uint4*)(kv8 + (size_t)csr_src[j + 5] * 1024 + (lane << 4));
    uint4 a6 = *(const uint4*)(kv8 + (size_t)csr_src[j + 6] * 1024 + (lane << 4));
    uint4 a7 = *(const uint4*)(kv8 + (size_t)csr_src[j + 7] * 1024 + (lane << 4));
    EDGE_A(a0)
    EDGE_A(a1)
    EDGE_A(a2)
    EDGE_A(a3)
    EDGE_A(a4)
    EDGE_A(a5)
    EDGE_A(a6)
    EDGE_A(a7)
  }
  for (; j + 3 < e1; j += 4) {
    uint4 a0 = *(const uint4*)(kv8 + (size_t)csr_src[j + 0] * 1024 + (lane << 4));
    uint4 a1 = *(const uint4*)(kv8 + (size_t)csr_src[j + 1] * 1024 + (lane << 4));
    uint4 a2 = *(const uint4*)(kv8 + (size_t)csr_src[j + 2] * 1024 + (lane << 4));
    uint4 a3 = *(const uint4*)(kv8 + (size_t)csr_src[j + 3] * 1024 + (lane << 4));
    EDGE_A(a0)
    EDGE_A(a1)
    EDGE_A(a2)
    EDGE_A(a3)
  }
  for (; j < e1; ++j) {
    uint4 a0 = *(const uint4*)(kv8 + (size_t)csr_src[j] * 1024 + (lane << 4));
    EDGE_A(a0)
  }

  float dAll = kl ? den : 0.f;
  float dv = __shfl_xor(dAll, 32);
  if (!kl) {
    float inv = 1.f / fmaxf(dv, 1e-16f);
    int c0 = vl << 4;
    float sk[16];
    uint4 s0 = *(const uint4*)(h1b + (size_t)n * 512 + c0);
    uint4 s1 = *(const uint4*)(h1b + (size_t)n * 512 + c0 + 8);
    unpack8(s0, sk); unpack8(s1, sk + 8);
    #pragma unroll
    for (int i = 0; i < 16; ++i)
      hl[ns][c0 + i] = fmaxf(sk[i] + acc[i] * inv, 0.f);
  }
  __syncthreads();

  // ---- layer-2 projections: j2 = lane&15, quarter = lane>>4 ----------------
  {
    const int j2 = lane & 15, qr = lane >> 4;
    const float* Wm4[4] = {Wq2, Wk2, Wv2, Ws2};
    const float* w = Wm4[j2 >> 2] + (size_t)(j2 & 3) * 512 + (qr << 7);
    const float* h = hl[ns] + (qr << 7);
    float p = 0.f;
    #pragma unroll
    for (int i = 0; i < 128; i += 4) {
      float4 wv = *(const float4*)(w + i);
      p += h[i] * wv.x + h[i+1] * wv.y + h[i+2] * wv.z + h[i+3] * wv.w;
    }
    p += __shfl_xor(p, 16);
    p += __shfl_xor(p, 32);
    if (lane < 16) {
      int sg = j2 >> 2, r = j2 & 3;
      const float* bb = (sg == 0) ? bq2 : (sg == 1) ? bk2
                      : (sg == 2) ? bv2 : bs2;
      float val = p + bb[r];
      if (sg < 3) qkv2[n * 12 + sg * 4 + r] = val;
      else        acc2[n * 4 + r] = val;
    }
  }
}

// ---- K5: layer-2 attention + skip + Wl dot + mean, fused -------------------
__global__ __launch_bounds__(256) void attn2_final(
    const float* __restrict__ qkv2, const int* __restrict__ rowptr,
    const int* __restrict__ csr_src, const float* __restrict__ acc2,
    const float* __restrict__ Wl, const float* __restrict__ bl,
    float* __restrict__ out)
{
  __shared__ float red[4];
  int t = blockIdx.x * 256 + threadIdx.x;   // grid covers NN*16 exactly
  int n = t >> 4, h = (t >> 2) & 3, part = t & 3;
  float q = qkv2[n * 12 + h];
  float den = 0.f, acc = 0.f;
  int e1 = rowptr[n + 1];
  for (int j = rowptr[n] + part; j < e1; j += 4) {
    int s = csr_src[j];
    float k = qkv2[s * 12 + 4 + h];
    float v = qkv2[s * 12 + 8 + h];
    float ex = __expf(q * k);
    den += ex; acc += ex * v;
  }
  den += __shfl_xor(den, 1); acc += __shfl_xor(acc, 1);
  den += __shfl_xor(den, 2); acc += __shfl_xor(acc, 2);
  float c = 0.f;
  if (part == 0)
    c = (acc2[n * 4 + h] + acc / fmaxf(den, 1e-16f)) * Wl[h] * (1.0f / NN);
  if (t == 0) c += bl[0];
  c += __shfl_xor(c, 4);
  c += __shfl_xor(c, 8);
  c += __shfl_xor(c, 16);
  c += __shfl_xor(c, 32);
  if ((threadIdx.x & 63) == 0) red[threadIdx.x >> 6] = c;
  __syncthreads();
  if (threadIdx.x == 0)
    unsafeAtomicAdd(out, red[0] + red[1] + red[2] + red[3]);
}

extern "C" void kernel_launch(void* const* d_in, const int* in_sizes, int n_in,
                              void* d_out, int out_size, void* d_ws, size_t ws_size,
                              hipStream_t stream)
{
  const float* x   = (const float*)d_in[0];
  const int*   ei  = (const int*)d_in[1];
  const float *Wq1 = (const float*)d_in[2],  *bq1 = (const float*)d_in[3];
  const float *Wk1 = (const float*)d_in[4],  *bk1 = (const float*)d_in[5];
  const float *Wv1 = (const float*)d_in[6],  *bv1 = (const float*)d_in[7];
  const float *Ws1 = (const float*)d_in[8],  *bs1 = (const float*)d_in[9];
  const float *Wq2 = (const float*)d_in[10], *bq2 = (const float*)d_in[11];
  const float *Wk2 = (const float*)d_in[12], *bk2 = (const float*)d_in[13];
  const float *Wv2 = (const float*)d_in[14], *bv2 = (const float*)d_in[15];
  const float *Ws2 = (const float*)d_in[16], *bs2 = (const float*)d_in[17];
  const float *Wl  = (const float*)d_in[18], *bl  = (const float*)d_in[19];
  const int* srcp = ei;
  const int* dstp = ei + NE;

  unsigned char* q8  = (unsigned char*)d_ws;           // NN*512 B
  unsigned char* kv8 = q8 + (size_t)NN * 512;          // NN*1024 B (k|v)
  ushort* x_bf = (ushort*)(kv8 + (size_t)NN * 1024);   // NN*128 bf16
  ushort* w1bf = x_bf + (size_t)NN * 128;              // 2048*128 bf16
  ushort* h1b  = w1bf + (size_t)2048 * 128;            // NN*512 bf16 (skip)
  float*  qkv2 = (float*)(h1b + (size_t)NN * 512);     // NN*12
  float*  acc2 = qkv2 + (size_t)NN * 12;               // NN*4
  int*   deg     = (int*)(acc2 + (size_t)NN * 4);      // NN
  int*   rowptr  = deg + NN;                           // NN+1
  int*   cursor  = rowptr + NN + 1;                    // NN
  int*   csr_src = cursor + NN;                        // NE

  zero_k<<<10, 1024, 0, stream>>>(deg, (float*)d_out);
  {
    const int total = NN * 32 + 4 * (512 * 128 / 4);
    prep_k<<<(total + 255) / 256, 256, 0, stream>>>(
        x, Wq1, Wk1, Wv1, Ws1, x_bf, w1bf, dstp, deg);
  }
  scan_k<<<1, 1024, 0, stream>>>(deg, rowptr, cursor);

  gemm_scatter<<<NGEMM + (NE + 255) / 256, 256, 0, stream>>>(
      x_bf, w1bf, bq1, bk1, bv1, bs1, q8, kv8, h1b,
      srcp, dstp, cursor, csr_src);

  attn_fused<<<NN / 4, 256, 0, stream>>>(
      q8, kv8, rowptr, csr_src, h1b,
      Wq2, bq2, Wk2, bk2, Wv2, bv2, Ws2, bs2, qkv2, acc2);

  attn2_final<<<NN * 16 / 256, 256, 0, stream>>>(
      qkv2, rowptr, csr_src, acc2, Wl, bl, (float*)d_out);
}

// Round 14
// 131.235 us; speedup vs baseline: 1.0418x; 1.0418x over previous
//
#include <hip/hip_runtime.h>
#include <math.h>

#define NN 10000
#define NE 160000
#define NROWT 79              // ceil(NN/128)
#define NCOLT 16              // 2048 cols / 128
#define NGEMM (NROWT * NCOLT)

typedef __attribute__((ext_vector_type(8))) short bf16x8;
typedef __attribute__((ext_vector_type(4))) float f32x4;
typedef __attribute__((ext_vector_type(2))) float f32x2;

#if defined(__has_builtin)
#if __has_builtin(__builtin_amdgcn_cvt_pk_fp8_f32) && __has_builtin(__builtin_amdgcn_cvt_pk_f32_fp8)
#define HW_FP8 1
#endif
#endif

__device__ inline ushort f2bf(float x) {
  uint u = __float_as_uint(x);
  return (ushort)((u + 0x7fffu + ((u >> 16) & 1u)) >> 16);
}
__device__ inline uint pk2bf(float a, float b) {
  return (uint)f2bf(a) | ((uint)f2bf(b) << 16);
}

__device__ inline void unpack8(uint4 u, float* f) {
  f[0] = __uint_as_float(u.x << 16); f[1] = __uint_as_float(u.x & 0xffff0000u);
  f[2] = __uint_as_float(u.y << 16); f[3] = __uint_as_float(u.y & 0xffff0000u);
  f[4] = __uint_as_float(u.z << 16); f[5] = __uint_as_float(u.z & 0xffff0000u);
  f[6] = __uint_as_float(u.w << 16); f[7] = __uint_as_float(u.w & 0xffff0000u);
}

#ifndef HW_FP8
__device__ inline float fp8_dec1(uint b) {
  uint s = b >> 7, e = (b >> 3) & 15, m = b & 7;
  float v = (e == 0) ? ldexpf((float)m, -9) : ldexpf((float)(8 + m), (int)e - 10);
  return s ? -v : v;
}
__device__ inline uint fp8_enc1(float x) {
  uint s = (__float_as_uint(x) >> 31) << 7;
  float a = fabsf(x);
  if (!(a < 448.f)) return s | 0x7e;
  if (a < 9.765625e-4f) return s;
  int e; float m = frexpf(a, &e);
  int E = e - 1, q;
  if (E < -6) {
    q = (int)rintf(ldexpf(a, 9));
    if (q == 0) return s;
    if (q >= 8) return s | 8;
    return s | (uint)q;
  }
  q = (int)rintf(ldexpf(m, 4));
  if (q == 16) { q = 8; ++E; }
  if (E > 8 || (E == 8 && q == 15)) return s | 0x7e;
  return s | ((uint)(E + 7) << 3) | (uint)(q - 8);
}
#endif

__device__ inline uint pack4_fp8(float a, float b, float c, float d) {
#ifdef HW_FP8
  uint w = (uint)__builtin_amdgcn_cvt_pk_fp8_f32(a, b, 0, false);
  w = (uint)__builtin_amdgcn_cvt_pk_fp8_f32(c, d, (int)w, true);
  return w;
#else
  return fp8_enc1(a) | (fp8_enc1(b) << 8) | (fp8_enc1(c) << 16) | (fp8_enc1(d) << 24);
#endif
}

__device__ inline void dec8_fp8(uint lo, uint hi, float* f) {
#ifdef HW_FP8
  f32x2 p0 = __builtin_amdgcn_cvt_pk_f32_fp8((int)lo, false);
  f32x2 p1 = __builtin_amdgcn_cvt_pk_f32_fp8((int)lo, true);
  f32x2 p2 = __builtin_amdgcn_cvt_pk_f32_fp8((int)hi, false);
  f32x2 p3 = __builtin_amdgcn_cvt_pk_f32_fp8((int)hi, true);
  f[0] = p0.x; f[1] = p0.y; f[2] = p1.x; f[3] = p1.y;
  f[4] = p2.x; f[5] = p2.y; f[6] = p3.x; f[7] = p3.y;
#else
  f[0] = fp8_dec1(lo & 255); f[1] = fp8_dec1((lo >> 8) & 255);
  f[2] = fp8_dec1((lo >> 16) & 255); f[3] = fp8_dec1(lo >> 24);
  f[4] = fp8_dec1(hi & 255); f[5] = fp8_dec1((hi >> 8) & 255);
  f[6] = fp8_dec1((hi >> 16) & 255); f[7] = fp8_dec1(hi >> 24);
#endif
}

__device__ inline void dec16(uint4 u, float* f) {
  dec8_fp8(u.x, u.y, f);
  dec8_fp8(u.z, u.w, f + 8);
}

// ---- K0: zero deg + d_out ---------------------------------------------------
__global__ __launch_bounds__(1024) void zero_k(
    int* __restrict__ deg, float* __restrict__ out)
{
  int i = blockIdx.x * 1024 + threadIdx.x;
  if (i < NN) deg[i] = 0;
  if (i == 0) out[0] = 0.f;
}

// ---- K1: degree count (global atomics) + fp32->bf16 conversions ------------
__global__ __launch_bounds__(256) void prep_k(
    const float* __restrict__ x,
    const float* __restrict__ Wq1, const float* __restrict__ Wk1,
    const float* __restrict__ Wv1, const float* __restrict__ Ws1,
    ushort* __restrict__ x_bf, ushort* __restrict__ w1bf,
    const int* __restrict__ dst, int* __restrict__ deg)
{
  int i = blockIdx.x * 256 + threadIdx.x;
  if (i < NE) atomicAdd(&deg[dst[i]], 1);
  const int n4x = NN * 32;
  const int n4w = 512 * 128 / 4;
  if (i < n4x) {
    float4 v = ((const float4*)x)[i];
    ushort4 o;
    o.x = f2bf(v.x); o.y = f2bf(v.y); o.z = f2bf(v.z); o.w = f2bf(v.w);
    ((ushort4*)x_bf)[i] = o;
  } else {
    int c = i - n4x;
    if (c < 4 * n4w) {
      int seg = c >> 14, k = c & 16383;
      const float* W = (seg == 0) ? Wq1 : (seg == 1) ? Wk1
                     : (seg == 2) ? Wv1 : Ws1;
      float4 v = ((const float4*)W)[k];
      ushort4 o;
      o.x = f2bf(v.x); o.y = f2bf(v.y); o.z = f2bf(v.z); o.w = f2bf(v.w);
      ((ushort4*)(w1bf + ((size_t)seg << 16)))[k] = o;
    }
  }
}

// ---- K2: CSR scan (shfl-based) ----------------------------------------------
__global__ __launch_bounds__(1024) void scan_k(
    const int* __restrict__ deg, int* __restrict__ rowptr,
    int* __restrict__ cursor)
{
  __shared__ int wsum[16];
  int tid = threadIdx.x;
  int base = tid * 10;
  int loc[10]; int s = 0;
  #pragma unroll
  for (int i = 0; i < 10; ++i) {
    int v = (base + i < NN) ? deg[base + i] : 0;
    loc[i] = s; s += v;
  }
  int mysum = s;
  #pragma unroll
  for (int d = 1; d < 64; d <<= 1) {
    int v = __shfl_up(s, d);
    if ((tid & 63) >= d) s += v;
  }
  if ((tid & 63) == 63) wsum[tid >> 6] = s;
  __syncthreads();
  int woff = 0;
  for (int w = 0; w < (tid >> 6); ++w) woff += wsum[w];
  int excl = woff + s - mysum;
  #pragma unroll
  for (int i = 0; i < 10; ++i) {
    int idx = base + i;
    if (idx < NN) { int r = excl + loc[i]; rowptr[idx] = r; cursor[idx] = r; }
  }
  if (tid == 1023) rowptr[NN] = woff + s;
}

// ---- K3: layer-1 GEMM 128x128 tiles (bf16 MFMA, fp8 out) + scatter ---------
__global__ __launch_bounds__(256) void gemm_scatter(
    const ushort* __restrict__ xbf, const ushort* __restrict__ wbf,
    const float* __restrict__ bq, const float* __restrict__ bk,
    const float* __restrict__ bv, const float* __restrict__ bs,
    unsigned char* __restrict__ q8, unsigned char* __restrict__ kv8,
    ushort* __restrict__ h1b,
    const int* __restrict__ src, const int* __restrict__ dst,
    int* __restrict__ cursor, int* __restrict__ csr_src)
{
  if (blockIdx.x >= NGEMM) {   // ---- scatter part ----
    int e = (blockIdx.x - NGEMM) * 256 + threadIdx.x;
    if (e < NE) {
      int pos = atomicAdd(&cursor[dst[e]], 1);
      csr_src[pos] = src[e];
    }
    return;
  }
  __shared__ __align__(16) ushort LDSbuf[32768];   // 64 KB: Al 32K | Bl 32K
  ushort* Al = LDSbuf;             // [128][128] swizzled
  ushort* Bl = LDSbuf + 16384;
  const int row0 = (blockIdx.x % NROWT) << 7;
  const int ncol0 = (blockIdx.x / NROWT) << 7;   // 0..1920
  const int tid = threadIdx.x;

  #pragma unroll
  for (int i = 0; i < 8; ++i) {
    int slot = tid + (i << 8);
    int r = slot >> 4, c = slot & 15;
    int gr = row0 + r;
    uint4 v = make_uint4(0u, 0u, 0u, 0u);
    if (gr < NN) v = *(const uint4*)(xbf + (size_t)gr * 128 + (c << 3));
    *(uint4*)(Al + r * 128 + ((c ^ (r & 7)) << 3)) = v;
  }
  #pragma unroll
  for (int i = 0; i < 8; ++i) {
    int slot = tid + (i << 8);
    int r = slot >> 4, c = slot & 15;
    uint4 v = *(const uint4*)(wbf + (size_t)(ncol0 + r) * 128 + (c << 3));
    *(uint4*)(Bl + r * 128 + ((c ^ (r & 7)) << 3)) = v;
  }
  __syncthreads();

  const int wv = tid >> 6, lane = tid & 63;
  const int lr = lane & 15, lkg = lane >> 4;
  const int seg = ncol0 >> 9;
  const int colInSeg = ncol0 & 511;
  const bool swp = (seg < 3);         // q,k,v -> fp8, D^T layout

  f32x4 acc[2][8];
  #pragma unroll
  for (int m = 0; m < 2; ++m)
    #pragma unroll
    for (int n = 0; n < 8; ++n) acc[m][n] = (f32x4){0.f, 0.f, 0.f, 0.f};

  #pragma unroll
  for (int ks = 0; ks < 4; ++ks) {
    int c16 = (ks << 2) + lkg;
    bf16x8 a[2], b[8];
    #pragma unroll
    for (int mf = 0; mf < 2; ++mf) {
      int r = (wv << 5) + (mf << 4) + lr;
      a[mf] = *(const bf16x8*)(Al + r * 128 + ((c16 ^ (r & 7)) << 3));
    }
    #pragma unroll
    for (int nf = 0; nf < 8; ++nf) {
      int r = (nf << 4) + lr;
      b[nf] = *(const bf16x8*)(Bl + r * 128 + ((c16 ^ (r & 7)) << 3));
    }
    if (swp) {
      #pragma unroll
      for (int mf = 0; mf < 2; ++mf)
        #pragma unroll
        for (int nf = 0; nf < 8; ++nf)
          acc[mf][nf] = __builtin_amdgcn_mfma_f32_16x16x32_bf16(
              b[nf], a[mf], acc[mf][nf], 0, 0, 0);
    } else {
      #pragma unroll
      for (int mf = 0; mf < 2; ++mf)
        #pragma unroll
        for (int nf = 0; nf < 8; ++nf)
          acc[mf][nf] = __builtin_amdgcn_mfma_f32_16x16x32_bf16(
              a[mf], b[nf], acc[mf][nf], 0, 0, 0);
    }
  }

  // ---- epilogue: two 64-col passes through S [128][68] f32 -----------------
  __syncthreads();                      // done reading Al/Bl
  float* S = (float*)LDSbuf;            // 34816 B
  const float* bias = (seg == 0) ? bq : (seg == 1) ? bk : (seg == 2) ? bv : bs;

  if (swp) {
    const float scale = (seg == 0) ? 0.08838834764831845f : 1.f;
    unsigned char* out8 = (seg == 0) ? q8 : kv8;
    const int rs = (seg == 0) ? 512 : 1024;
    const int choff = ((seg == 2) ? 512 : 0) + colInSeg;
    #pragma unroll
    for (int pass = 0; pass < 2; ++pass) {
      #pragma unroll
      for (int mf = 0; mf < 2; ++mf) {
        int rl = (wv << 5) + (mf << 4) + lr;
        #pragma unroll
        for (int nf2 = 0; nf2 < 4; ++nf2) {
          int nf = (pass << 2) + nf2;
          int cl = (nf << 4) + (lkg << 2);          // 0..127
          float4 bb = *(const float4*)(bias + colInSeg + cl);
          float4 o;
          o.x = (acc[mf][nf][0] + bb.x) * scale;
          o.y = (acc[mf][nf][1] + bb.y) * scale;
          o.z = (acc[mf][nf][2] + bb.z) * scale;
          o.w = (acc[mf][nf][3] + bb.w) * scale;
          *(float4*)(S + rl * 68 + (cl - (pass << 6))) = o;
        }
      }
      __syncthreads();
      for (int tt = tid; tt < 512; tt += 256) {
        int row = tt >> 2, q4 = (tt & 3) << 4;
        int grow = row0 + row;
        if (grow < NN) {
          const float* p = S + row * 68 + q4;
          uint4 w;
          w.x = pack4_fp8(p[0],  p[1],  p[2],  p[3]);
          w.y = pack4_fp8(p[4],  p[5],  p[6],  p[7]);
          w.z = pack4_fp8(p[8],  p[9],  p[10], p[11]);
          w.w = pack4_fp8(p[12], p[13], p[14], p[15]);
          *(uint4*)(out8 + (size_t)grow * rs + choff + (pass << 6) + q4) = w;
        }
      }
      __syncthreads();
    }
  } else {
    #pragma unroll
    for (int pass = 0; pass < 2; ++pass) {
      #pragma unroll
      for (int mf = 0; mf < 2; ++mf) {
        #pragma unroll
        for (int nf2 = 0; nf2 < 4; ++nf2) {
          int nf = (pass << 2) + nf2;
          int cl = (nf << 4) + lr;
          float bb = bias[colInSeg + cl];
          #pragma unroll
          for (int r = 0; r < 4; ++r) {
            int rl = (wv << 5) + (mf << 4) + (lkg << 2) + r;
            S[rl * 68 + (cl - (pass << 6))] = acc[mf][nf][r] + bb;
          }
        }
      }
      __syncthreads();
      for (int tt = tid; tt < 1024; tt += 256) {
        int row = tt >> 3, g = tt & 7;
        int grow = row0 + row;
        if (grow < NN) {
          const float* p = S + row * 68 + (g << 3);
          uint4 w;
          w.x = pk2bf(p[0], p[1]);
          w.y = pk2bf(p[2], p[3]);
          w.z = pk2bf(p[4], p[5]);
          w.w = pk2bf(p[6], p[7]);
          *(uint4*)(h1b + (size_t)grow * 512 + colInSeg + (pass << 6) + (g << 3)) = w;
        }
      }
      __syncthreads();
    }
  }
}

// ---- K4: layer-1 attention: 1 wave per node, unroll-8, no LDS --------------
#define EDGE_A(kvreg)                                                      \
  {                                                                        \
    float f[16]; dec16(kvreg, f);                                          \
    float t = qf[0]*f[0]+qf[1]*f[1]+qf[2]*f[2]+qf[3]*f[3]                  \
            + qf[4]*f[4]+qf[5]*f[5]+qf[6]*f[6]+qf[7]*f[7]                  \
            + qf[8]*f[8]+qf[9]*f[9]+qf[10]*f[10]+qf[11]*f[11]              \
            + qf[12]*f[12]+qf[13]*f[13]+qf[14]*f[14]+qf[15]*f[15];         \
    t += __shfl_xor(t, 1);                                                 \
    t += __shfl_xor(t, 2);                                                 \
    t += __shfl_xor(t, 4);                                                 \
    float exA = __expf(t);                                                 \
    float exO = __shfl_xor(exA, 32);                                       \
    if (kl) den += exA;                                                    \
    float exV = kl ? 0.f : exO;                                            \
    _Pragma("unroll")                                                      \
    for (int i = 0; i < 16; ++i) acc[i] = fmaf(exV, f[i], acc[i]);         \
  }

__global__ __launch_bounds__(256) void attn1(
    const unsigned char* __restrict__ q8, const unsigned char* __restrict__ kv8,
    const int* __restrict__ rowptr, const int* __restrict__ csr_src,
    ushort* __restrict__ h1b)
{
  const int n = blockIdx.x * 4 + (threadIdx.x >> 6);
  const int lane = threadIdx.x & 63;
  const bool kl = lane < 32;
  const int vl = lane & 31;

  float qf[16];
  if (kl) {
    uint4 qv = *(const uint4*)(q8 + (size_t)n * 512 + (lane << 4));
    dec16(qv, qf);
  } else {
    #pragma unroll
    for (int i = 0; i < 16; ++i) qf[i] = 0.f;
  }

  float acc[16] = {};
  float den = 0.f;
  int j = rowptr[n];
  const int e1 = rowptr[n + 1];
  for (; j + 7 < e1; j += 8) {
    uint4 a0 = *(const uint4*)(kv8 + (size_t)csr_src[j + 0] * 1024 + (lane << 4));
    uint4 a1 = *(const uint4*)(kv8 + (size_t)csr_src[j + 1] * 1024 + (lane << 4));
    uint4 a2 = *(const uint4*)(kv8 + (size_t)csr_src[j + 2] * 1024 + (lane << 4));
    uint4 a3 = *(const uint4*)(kv8 + (size_t)csr_src[j + 3] * 1024 + (lane << 4));
    uint4 a4 = *(const uint4*)(kv8 + (size_t)csr_src[j + 4] * 1024 + (lane << 4));
    uint4 a5 = *(const uint4*)(kv8 + (size_t)csr_src[j + 5] * 1024 + (lane << 4));
    uint4 a6 = *(const uint4*)(kv8 + (size_t)csr_src[j + 6] * 1024 + (lane << 4));
    uint4 a7 = *(const uint4*)(kv8 + (size_t)csr_src[j + 7] * 1024 + (lane << 4));
    EDGE_A(a0)
    EDGE_A(a1)
    EDGE_A(a2)
    EDGE_A(a3)
    EDGE_A(a4)
    EDGE_A(a5)
    EDGE_A(a6)
    EDGE_A(a7)
  }
  for (; j + 3 < e1; j += 4) {
    uint4 a0 = *(const uint4*)(kv8 + (size_t)csr_src[j + 0] * 1024 + (lane << 4));
    uint4 a1 = *(const uint4*)(kv8 + (size_t)csr_src[j + 1] * 1024 + (lane << 4));
    uint4 a2 = *(const uint4*)(kv8 + (size_t)csr_src[j + 2] * 1024 + (lane << 4));
    uint4 a3 = *(const uint4*)(kv8 + (size_t)csr_src[j + 3] * 1024 + (lane << 4));
    EDGE_A(a0)
    EDGE_A(a1)
    EDGE_A(a2)
    EDGE_A(a3)
  }
  for (; j < e1; ++j) {
    uint4 a0 = *(const uint4*)(kv8 + (size_t)csr_src[j] * 1024 + (lane << 4));
    EDGE_A(a0)
  }

  float dAll = kl ? den : 0.f;
  float dv = __shfl_xor(dAll, 32);
  if (!kl) {
    float inv = 1.f / fmaxf(dv, 1e-16f);
    int c0 = vl << 4;
    float sk[16];
    uint4 s0 = *(const uint4*)(h1b + (size_t)n * 512 + c0);
    uint4 s1 = *(const uint4*)(h1b + (size_t)n * 512 + c0 + 8);
    unpack8(s0, sk); unpack8(s1, sk + 8);
    ushort o[16];
    #pragma unroll
    for (int i = 0; i < 16; ++i)
      o[i] = f2bf(fmaxf(sk[i] + acc[i] * inv, 0.f));
    uint4 w0, w1;
    w0.x = (uint)o[0]  | ((uint)o[1]  << 16);
    w0.y = (uint)o[2]  | ((uint)o[3]  << 16);
    w0.z = (uint)o[4]  | ((uint)o[5]  << 16);
    w0.w = (uint)o[6]  | ((uint)o[7]  << 16);
    w1.x = (uint)o[8]  | ((uint)o[9]  << 16);
    w1.y = (uint)o[10] | ((uint)o[11] << 16);
    w1.z = (uint)o[12] | ((uint)o[13] << 16);
    w1.w = (uint)o[14] | ((uint)o[15] << 16);
    *(uint4*)(h1b + (size_t)n * 512 + c0) = w0;
    *(uint4*)(h1b + (size_t)n * 512 + c0 + 8) = w1;
  }
}

// ---- K5: layer-2 projections (bf16 h1, wave-uniform W loads) ---------------
__global__ __launch_bounds__(256) void gemm_l2(
    const ushort* __restrict__ h1b,
    const float* __restrict__ Wq, const float* __restrict__ bq,
    const float* __restrict__ Wk, const float* __restrict__ bk,
    const float* __restrict__ Wv, const float* __restrict__ bv,
    const float* __restrict__ Ws, const float* __restrict__ bs,
    float* __restrict__ qkv2, float* __restrict__ acc2)
{
  __shared__ float red[4][64][17];
  int n0 = blockIdx.x * 64;
  int wid = threadIdx.x >> 6, lane = threadIdx.x & 63;
  int n = n0 + lane;
  const float* Wm[4] = {Wq, Wk, Wv, Ws};
  float s[16] = {};
  if (n < NN) {
    const ushort* a = h1b + (size_t)n * 512 + wid * 128;
    #pragma unroll 2
    for (int i = 0; i < 128; i += 8) {
      uint4 hv = *(const uint4*)(a + i);
      float av[8]; unpack8(hv, av);
      #pragma unroll
      for (int j = 0; j < 16; ++j) {
        const float* w = Wm[j >> 2] + (size_t)(j & 3) * 512 + wid * 128 + i;
        s[j] += av[0]*w[0] + av[1]*w[1] + av[2]*w[2] + av[3]*w[3]
              + av[4]*w[4] + av[5]*w[5] + av[6]*w[6] + av[7]*w[7];
      }
    }
  }
  #pragma unroll
  for (int j = 0; j < 16; ++j) red[wid][lane][j] = s[j];
  __syncthreads();
  #pragma unroll
  for (int q = 0; q < 4; ++q) {
    int idx = threadIdx.x * 4 + q;
    int ln = idx >> 4, j = idx & 15;
    int nn2 = n0 + ln;
    if (nn2 >= NN) continue;
    float v = red[0][ln][j] + red[1][ln][j] + red[2][ln][j] + red[3][ln][j];
    int sg = j >> 2, r = j & 3;
    const float* bb = (sg == 0) ? bq : (sg == 1) ? bk : (sg == 2) ? bv : bs;
    v += bb[r];
    if (sg < 3) qkv2[nn2 * 12 + sg * 4 + r] = v;
    else        acc2[nn2 * 4 + r] = v;
  }
}

// ---- K6: layer-2 attention + skip + Wl dot + mean, fused -------------------
__global__ __launch_bounds__(256) void attn2_final(
    const float* __restrict__ qkv2, const int* __restrict__ rowptr,
    const int* __restrict__ csr_src, const float* __restrict__ acc2,
    const float* __restrict__ Wl, const float* __restrict__ bl,
    float* __restrict__ out)
{
  __shared__ float red[4];
  int t = blockIdx.x * 256 + threadIdx.x;   // grid covers NN*16 exactly
  int n = t >> 4, h = (t >> 2) & 3, part = t & 3;
  float q = qkv2[n * 12 + h];
  float den = 0.f, acc = 0.f;
  int e1 = rowptr[n + 1];
  for (int j = rowptr[n] + part; j < e1; j += 4) {
    int s = csr_src[j];
    float k = qkv2[s * 12 + 4 + h];
    float v = qkv2[s * 12 + 8 + h];
    float ex = __expf(q * k);
    den += ex; acc += ex * v;
  }
  den += __shfl_xor(den, 1); acc += __shfl_xor(acc, 1);
  den += __shfl_xor(den, 2); acc += __shfl_xor(acc, 2);
  float c = 0.f;
  if (part == 0)
    c = (acc2[n * 4 + h] + acc / fmaxf(den, 1e-16f)) * Wl[h] * (1.0f / NN);
  if (t == 0) c += bl[0];
  c += __shfl_xor(c, 4);
  c += __shfl_xor(c, 8);
  c += __shfl_xor(c, 16);
  c += __shfl_xor(c, 32);
  if ((threadIdx.x & 63) == 0) red[threadIdx.x >> 6] = c;
  __syncthreads();
  if (threadIdx.x == 0)
    unsafeAtomicAdd(out, red[0] + red[1] + red[2] + red[3]);
}

extern "C" void kernel_launch(void* const* d_in, const int* in_sizes, int n_in,
                              void* d_out, int out_size, void* d_ws, size_t ws_size,
                              hipStream_t stream)
{
  const float* x   = (const float*)d_in[0];
  const int*   ei  = (const int*)d_in[1];
  const float *Wq1 = (const float*)d_in[2],  *bq1 = (const float*)d_in[3];
  const float *Wk1 = (const float*)d_in[4],  *bk1 = (const float*)d_in[5];
  const float *Wv1 = (const float*)d_in[6],  *bv1 = (const float*)d_in[7];
  const float *Ws1 = (const float*)d_in[8],  *bs1 = (const float*)d_in[9];
  const float *Wq2 = (const float*)d_in[10], *bq2 = (const float*)d_in[11];
  const float *Wk2 = (const float*)d_in[12], *bk2 = (const float*)d_in[13];
  const float *Wv2 = (const float*)d_in[14], *bv2 = (const float*)d_in[15];
  const float *Ws2 = (const float*)d_in[16], *bs2 = (const float*)d_in[17];
  const float *Wl  = (const float*)d_in[18], *bl  = (const float*)d_in[19];
  const int* srcp = ei;
  const int* dstp = ei + NE;

  unsigned char* q8  = (unsigned char*)d_ws;           // NN*512 B
  unsigned char* kv8 = q8 + (size_t)NN * 512;          // NN*1024 B (k|v)
  ushort* x_bf = (ushort*)(kv8 + (size_t)NN * 1024);   // NN*128 bf16
  ushort* w1bf = x_bf + (size_t)NN * 128;              // 2048*128 bf16
  ushort* h1b  = w1bf + (size_t)2048 * 128;            // NN*512 bf16
  float*  qkv2 = (float*)(h1b + (size_t)NN * 512);     // NN*12
  float*  acc2 = qkv2 + (size_t)NN * 12;               // NN*4
  int*   deg     = (int*)(acc2 + (size_t)NN * 4);      // NN
  int*   rowptr  = deg + NN;                           // NN+1
  int*   cursor  = rowptr + NN + 1;                    // NN
  int*   csr_src = cursor + NN;                        // NE

  zero_k<<<10, 1024, 0, stream>>>(deg, (float*)d_out);
  {
    const int total = NN * 32 + 4 * (512 * 128 / 4);
    prep_k<<<(total + 255) / 256, 256, 0, stream>>>(
        x, Wq1, Wk1, Wv1, Ws1, x_bf, w1bf, dstp, deg);
  }
  scan_k<<<1, 1024, 0, stream>>>(deg, rowptr, cursor);

  gemm_scatter<<<NGEMM + (NE + 255) / 256, 256, 0, stream>>>(
      x_bf, w1bf, bq1, bk1, bv1, bs1, q8, kv8, h1b,
      srcp, dstp, cursor, csr_src);

  attn1<<<NN / 4, 256, 0, stream>>>(q8, kv8, rowptr, csr_src, h1b);

  gemm_l2<<<(NN + 63) / 64, 256, 0, stream>>>(
      h1b, Wq2, bq2, Wk2, bk2, Wv2, bv2, Ws2, bs2, qkv2, acc2);

  attn2_final<<<NN * 16 / 256, 256, 0, stream>>>(
      qkv2, rowptr, csr_src, acc2, Wl, bl, (float*)d_out);
}

// Round 15
// 130.015 us; speedup vs baseline: 1.0516x; 1.0094x over previous
//
#include <hip/hip_runtime.h>
#include <math.h>

#define NN 10000
#define NE 160000
#define NROWT 79              // ceil(NN/128)
#define NCOLT 16              // 2048 cols / 128
#define NGEMM (NROWT * NCOLT)

typedef __attribute__((ext_vector_type(8))) short bf16x8;
typedef __attribute__((ext_vector_type(4))) float f32x4;
typedef __attribute__((ext_vector_type(2))) float f32x2;

#if defined(__has_builtin)
#if __has_builtin(__builtin_amdgcn_cvt_pk_fp8_f32) && __has_builtin(__builtin_amdgcn_cvt_pk_f32_fp8)
#define HW_FP8 1
#endif
#endif

__device__ inline ushort f2bf(float x) {
  uint u = __float_as_uint(x);
  return (ushort)((u + 0x7fffu + ((u >> 16) & 1u)) >> 16);
}
__device__ inline uint pk2bf(float a, float b) {
  return (uint)f2bf(a) | ((uint)f2bf(b) << 16);
}

__device__ inline void unpack8(uint4 u, float* f) {
  f[0] = __uint_as_float(u.x << 16); f[1] = __uint_as_float(u.x & 0xffff0000u);
  f[2] = __uint_as_float(u.y << 16); f[3] = __uint_as_float(u.y & 0xffff0000u);
  f[4] = __uint_as_float(u.z << 16); f[5] = __uint_as_float(u.z & 0xffff0000u);
  f[6] = __uint_as_float(u.w << 16); f[7] = __uint_as_float(u.w & 0xffff0000u);
}

#ifndef HW_FP8
__device__ inline float fp8_dec1(uint b) {
  uint s = b >> 7, e = (b >> 3) & 15, m = b & 7;
  float v = (e == 0) ? ldexpf((float)m, -9) : ldexpf((float)(8 + m), (int)e - 10);
  return s ? -v : v;
}
__device__ inline uint fp8_enc1(float x) {
  uint s = (__float_as_uint(x) >> 31) << 7;
  float a = fabsf(x);
  if (!(a < 448.f)) return s | 0x7e;
  if (a < 9.765625e-4f) return s;
  int e; float m = frexpf(a, &e);
  int E = e - 1, q;
  if (E < -6) {
    q = (int)rintf(ldexpf(a, 9));
    if (q == 0) return s;
    if (q >= 8) return s | 8;
    return s | (uint)q;
  }
  q = (int)rintf(ldexpf(m, 4));
  if (q == 16) { q = 8; ++E; }
  if (E > 8 || (E == 8 && q == 15)) return s | 0x7e;
  return s | ((uint)(E + 7) << 3) | (uint)(q - 8);
}
#endif

__device__ inline uint pack4_fp8(float a, float b, float c, float d) {
#ifdef HW_FP8
  uint w = (uint)__builtin_amdgcn_cvt_pk_fp8_f32(a, b, 0, false);
  w = (uint)__builtin_amdgcn_cvt_pk_fp8_f32(c, d, (int)w, true);
  return w;
#else
  return fp8_enc1(a) | (fp8_enc1(b) << 8) | (fp8_enc1(c) << 16) | (fp8_enc1(d) << 24);
#endif
}

__device__ inline void dec8_fp8(uint lo, uint hi, float* f) {
#ifdef HW_FP8
  f32x2 p0 = __builtin_amdgcn_cvt_pk_f32_fp8((int)lo, false);
  f32x2 p1 = __builtin_amdgcn_cvt_pk_f32_fp8((int)lo, true);
  f32x2 p2 = __builtin_amdgcn_cvt_pk_f32_fp8((int)hi, false);
  f32x2 p3 = __builtin_amdgcn_cvt_pk_f32_fp8((int)hi, true);
  f[0] = p0.x; f[1] = p0.y; f[2] = p1.x; f[3] = p1.y;
  f[4] = p2.x; f[5] = p2.y; f[6] = p3.x; f[7] = p3.y;
#else
  f[0] = fp8_dec1(lo & 255); f[1] = fp8_dec1((lo >> 8) & 255);
  f[2] = fp8_dec1((lo >> 16) & 255); f[3] = fp8_dec1(lo >> 24);
  f[4] = fp8_dec1(hi & 255); f[5] = fp8_dec1((hi >> 8) & 255);
  f[6] = fp8_dec1((hi >> 16) & 255); f[7] = fp8_dec1(hi >> 24);
#endif
}

__device__ inline void dec16(uint4 u, float* f) {
  dec8_fp8(u.x, u.y, f);
  dec8_fp8(u.z, u.w, f + 8);
}

// ---- K0: zero deg + d_out ---------------------------------------------------
__global__ __launch_bounds__(1024) void zero_k(
    int* __restrict__ deg, float* __restrict__ out)
{
  int i = blockIdx.x * 1024 + threadIdx.x;
  if (i < NN) deg[i] = 0;
  if (i == 0) out[0] = 0.f;
}

// ---- K1: degree count (global atomics) + fp32->bf16 conversions ------------
__global__ __launch_bounds__(256) void prep_k(
    const float* __restrict__ x,
    const float* __restrict__ Wq1, const float* __restrict__ Wk1,
    const float* __restrict__ Wv1, const float* __restrict__ Ws1,
    ushort* __restrict__ x_bf, ushort* __restrict__ w1bf,
    const int* __restrict__ dst, int* __restrict__ deg)
{
  int i = blockIdx.x * 256 + threadIdx.x;
  if (i < NE) atomicAdd(&deg[dst[i]], 1);
  const int n4x = NN * 32;
  const int n4w = 512 * 128 / 4;
  if (i < n4x) {
    float4 v = ((const float4*)x)[i];
    ushort4 o;
    o.x = f2bf(v.x); o.y = f2bf(v.y); o.z = f2bf(v.z); o.w = f2bf(v.w);
    ((ushort4*)x_bf)[i] = o;
  } else {
    int c = i - n4x;
    if (c < 4 * n4w) {
      int seg = c >> 14, k = c & 16383;
      const float* W = (seg == 0) ? Wq1 : (seg == 1) ? Wk1
                     : (seg == 2) ? Wv1 : Ws1;
      float4 v = ((const float4*)W)[k];
      ushort4 o;
      o.x = f2bf(v.x); o.y = f2bf(v.y); o.z = f2bf(v.z); o.w = f2bf(v.w);
      ((ushort4*)(w1bf + ((size_t)seg << 16)))[k] = o;
    }
  }
}

// ---- K2: CSR scan (shfl-based) ----------------------------------------------
__global__ __launch_bounds__(1024) void scan_k(
    const int* __restrict__ deg, int* __restrict__ rowptr,
    int* __restrict__ cursor)
{
  __shared__ int wsum[16];
  int tid = threadIdx.x;
  int base = tid * 10;
  int loc[10]; int s = 0;
  #pragma unroll
  for (int i = 0; i < 10; ++i) {
    int v = (base + i < NN) ? deg[base + i] : 0;
    loc[i] = s; s += v;
  }
  int mysum = s;
  #pragma unroll
  for (int d = 1; d < 64; d <<= 1) {
    int v = __shfl_up(s, d);
    if ((tid & 63) >= d) s += v;
  }
  if ((tid & 63) == 63) wsum[tid >> 6] = s;
  __syncthreads();
  int woff = 0;
  for (int w = 0; w < (tid >> 6); ++w) woff += wsum[w];
  int excl = woff + s - mysum;
  #pragma unroll
  for (int i = 0; i < 10; ++i) {
    int idx = base + i;
    if (idx < NN) { int r = excl + loc[i]; rowptr[idx] = r; cursor[idx] = r; }
  }
  if (tid == 1023) rowptr[NN] = woff + s;
}

// ---- K3: layer-1 GEMM 128x128 tiles (bf16 MFMA, fp8 out) + scatter ---------
__global__ __launch_bounds__(256) void gemm_scatter(
    const ushort* __restrict__ xbf, const ushort* __restrict__ wbf,
    const float* __restrict__ bq, const float* __restrict__ bk,
    const float* __restrict__ bv, const float* __restrict__ bs,
    unsigned char* __restrict__ q8, unsigned char* __restrict__ kv8,
    ushort* __restrict__ h1b,
    const int* __restrict__ src, const int* __restrict__ dst,
    int* __restrict__ cursor, int* __restrict__ csr_src)
{
  if (blockIdx.x >= NGEMM) {   // ---- scatter part ----
    int e = (blockIdx.x - NGEMM) * 256 + threadIdx.x;
    if (e < NE) {
      int pos = atomicAdd(&cursor[dst[e]], 1);
      csr_src[pos] = src[e];
    }
    return;
  }
  __shared__ __align__(16) ushort LDSbuf[32768];   // 64 KB: Al 32K | Bl 32K
  ushort* Al = LDSbuf;             // [128][128] swizzled
  ushort* Bl = LDSbuf + 16384;
  const int row0 = (blockIdx.x % NROWT) << 7;
  const int ncol0 = (blockIdx.x / NROWT) << 7;   // 0..1920
  const int tid = threadIdx.x;

  #pragma unroll
  for (int i = 0; i < 8; ++i) {
    int slot = tid + (i << 8);
    int r = slot >> 4, c = slot & 15;
    int gr = row0 + r;
    uint4 v = make_uint4(0u, 0u, 0u, 0u);
    if (gr < NN) v = *(const uint4*)(xbf + (size_t)gr * 128 + (c << 3));
    *(uint4*)(Al + r * 128 + ((c ^ (r & 7)) << 3)) = v;
  }
  #pragma unroll
  for (int i = 0; i < 8; ++i) {
    int slot = tid + (i << 8);
    int r = slot >> 4, c = slot & 15;
    uint4 v = *(const uint4*)(wbf + (size_t)(ncol0 + r) * 128 + (c << 3));
    *(uint4*)(Bl + r * 128 + ((c ^ (r & 7)) << 3)) = v;
  }
  __syncthreads();

  const int wv = tid >> 6, lane = tid & 63;
  const int lr = lane & 15, lkg = lane >> 4;
  const int seg = ncol0 >> 9;
  const int colInSeg = ncol0 & 511;
  const bool swp = (seg < 3);         // q,k,v -> fp8, D^T layout

  f32x4 acc[2][8];
  #pragma unroll
  for (int m = 0; m < 2; ++m)
    #pragma unroll
    for (int n = 0; n < 8; ++n) acc[m][n] = (f32x4){0.f, 0.f, 0.f, 0.f};

  #pragma unroll
  for (int ks = 0; ks < 4; ++ks) {
    int c16 = (ks << 2) + lkg;
    bf16x8 a[2], b[8];
    #pragma unroll
    for (int mf = 0; mf < 2; ++mf) {
      int r = (wv << 5) + (mf << 4) + lr;
      a[mf] = *(const bf16x8*)(Al + r * 128 + ((c16 ^ (r & 7)) << 3));
    }
    #pragma unroll
    for (int nf = 0; nf < 8; ++nf) {
      int r = (nf << 4) + lr;
      b[nf] = *(const bf16x8*)(Bl + r * 128 + ((c16 ^ (r & 7)) << 3));
    }
    if (swp) {
      #pragma unroll
      for (int mf = 0; mf < 2; ++mf)
        #pragma unroll
        for (int nf = 0; nf < 8; ++nf)
          acc[mf][nf] = __builtin_amdgcn_mfma_f32_16x16x32_bf16(
              b[nf], a[mf], acc[mf][nf], 0, 0, 0);
    } else {
      #pragma unroll
      for (int mf = 0; mf < 2; ++mf)
        #pragma unroll
        for (int nf = 0; nf < 8; ++nf)
          acc[mf][nf] = __builtin_amdgcn_mfma_f32_16x16x32_bf16(
              a[mf], b[nf], acc[mf][nf], 0, 0, 0);
    }
  }

  // ---- epilogue: two 64-col passes through S [128][68] f32 -----------------
  __syncthreads();                      // done reading Al/Bl
  float* S = (float*)LDSbuf;            // 34816 B
  const float* bias = (seg == 0) ? bq : (seg == 1) ? bk : (seg == 2) ? bv : bs;

  if (swp) {
    const float scale = (seg == 0) ? 0.08838834764831845f : 1.f;
    unsigned char* out8 = (seg == 0) ? q8 : kv8;
    const int rs = (seg == 0) ? 512 : 1024;
    const int choff = ((seg == 2) ? 512 : 0) + colInSeg;
    #pragma unroll
    for (int pass = 0; pass < 2; ++pass) {
      #pragma unroll
      for (int mf = 0; mf < 2; ++mf) {
        int rl = (wv << 5) + (mf << 4) + lr;
        #pragma unroll
        for (int nf2 = 0; nf2 < 4; ++nf2) {
          int nf = (pass << 2) + nf2;
          int cl = (nf << 4) + (lkg << 2);          // 0..127
          float4 bb = *(const float4*)(bias + colInSeg + cl);
          float4 o;
          o.x = (acc[mf][nf][0] + bb.x) * scale;
          o.y = (acc[mf][nf][1] + bb.y) * scale;
          o.z = (acc[mf][nf][2] + bb.z) * scale;
          o.w = (acc[mf][nf][3] + bb.w) * scale;
          *(float4*)(S + rl * 68 + (cl - (pass << 6))) = o;
        }
      }
      __syncthreads();
      for (int tt = tid; tt < 512; tt += 256) {
        int row = tt >> 2, q4 = (tt & 3) << 4;
        int grow = row0 + row;
        if (grow < NN) {
          const float* p = S + row * 68 + q4;
          uint4 w;
          w.x = pack4_fp8(p[0],  p[1],  p[2],  p[3]);
          w.y = pack4_fp8(p[4],  p[5],  p[6],  p[7]);
          w.z = pack4_fp8(p[8],  p[9],  p[10], p[11]);
          w.w = pack4_fp8(p[12], p[13], p[14], p[15]);
          *(uint4*)(out8 + (size_t)grow * rs + choff + (pass << 6) + q4) = w;
        }
      }
      __syncthreads();
    }
  } else {
    #pragma unroll
    for (int pass = 0; pass < 2; ++pass) {
      #pragma unroll
      for (int mf = 0; mf < 2; ++mf) {
        #pragma unroll
        for (int nf2 = 0; nf2 < 4; ++nf2) {
          int nf = (pass << 2) + nf2;
          int cl = (nf << 4) + lr;
          float bb = bias[colInSeg + cl];
          #pragma unroll
          for (int r = 0; r < 4; ++r) {
            int rl = (wv << 5) + (mf << 4) + (lkg << 2) + r;
            S[rl * 68 + (cl - (pass << 6))] = acc[mf][nf][r] + bb;
          }
        }
      }
      __syncthreads();
      for (int tt = tid; tt < 1024; tt += 256) {
        int row = tt >> 3, g = tt & 7;
        int grow = row0 + row;
        if (grow < NN) {
          const float* p = S + row * 68 + (g << 3);
          uint4 w;
          w.x = pk2bf(p[0], p[1]);
          w.y = pk2bf(p[2], p[3]);
          w.z = pk2bf(p[4], p[5]);
          w.w = pk2bf(p[6], p[7]);
          *(uint4*)(h1b + (size_t)grow * 512 + colInSeg + (pass << 6) + (g << 3)) = w;
        }
      }
      __syncthreads();
    }
  }
}

// ---- K4: layer-1 attention: 1 wave per node, unroll-8, no LDS --------------
#define EDGE_A(kvreg)                                                      \
  {                                                                        \
    float f[16]; dec16(kvreg, f);                                          \
    float t = qf[0]*f[0]+qf[1]*f[1]+qf[2]*f[2]+qf[3]*f[3]                  \
            + qf[4]*f[4]+qf[5]*f[5]+qf[6]*f[6]+qf[7]*f[7]                  \
            + qf[8]*f[8]+qf[9]*f[9]+qf[10]*f[10]+qf[11]*f[11]              \
            + qf[12]*f[12]+qf[13]*f[13]+qf[14]*f[14]+qf[15]*f[15];         \
    t += __shfl_xor(t, 1);                                                 \
    t += __shfl_xor(t, 2);                                                 \
    t += __shfl_xor(t, 4);                                                 \
    float exA = __expf(t);                                                 \
    float exO = __shfl_xor(exA, 32);                                       \
    if (kl) den += exA;                                                    \
    float exV = kl ? 0.f : exO;                                            \
    _Pragma("unroll")                                                      \
    for (int i = 0; i < 16; ++i) acc[i] = fmaf(exV, f[i], acc[i]);         \
  }

__global__ __launch_bounds__(256) void attn1(
    const unsigned char* __restrict__ q8, const unsigned char* __restrict__ kv8,
    const int* __restrict__ rowptr, const int* __restrict__ csr_src,
    ushort* __restrict__ h1b)
{
  const int n = blockIdx.x * 4 + (threadIdx.x >> 6);
  const int lane = threadIdx.x & 63;
  const bool kl = lane < 32;
  const int vl = lane & 31;

  float qf[16];
  if (kl) {
    uint4 qv = *(const uint4*)(q8 + (size_t)n * 512 + (lane << 4));
    dec16(qv, qf);
  } else {
    #pragma unroll
    for (int i = 0; i < 16; ++i) qf[i] = 0.f;
  }

  float acc[16] = {};
  float den = 0.f;
  int j = rowptr[n];
  const int e1 = rowptr[n + 1];
  for (; j + 7 < e1; j += 8) {
    uint4 a0 = *(const uint4*)(kv8 + (size_t)csr_src[j + 0] * 1024 + (lane << 4));
    uint4 a1 = *(const uint4*)(kv8 + (size_t)csr_src[j + 1] * 1024 + (lane << 4));
    uint4 a2 = *(const uint4*)(kv8 + (size_t)csr_src[j + 2] * 1024 + (lane << 4));
    uint4 a3 = *(const uint4*)(kv8 + (size_t)csr_src[j + 3] * 1024 + (lane << 4));
    uint4 a4 = *(const uint4*)(kv8 + (size_t)csr_src[j + 4] * 1024 + (lane << 4));
    uint4 a5 = *(const uint4*)(kv8 + (size_t)csr_src[j + 5] * 1024 + (lane << 4));
    uint4 a6 = *(const uint4*)(kv8 + (size_t)csr_src[j + 6] * 1024 + (lane << 4));
    uint4 a7 = *(const uint4*)(kv8 + (size_t)csr_src[j + 7] * 1024 + (lane << 4));
    EDGE_A(a0)
    EDGE_A(a1)
    EDGE_A(a2)
    EDGE_A(a3)
    EDGE_A(a4)
    EDGE_A(a5)
    EDGE_A(a6)
    EDGE_A(a7)
  }
  for (; j + 3 < e1; j += 4) {
    uint4 a0 = *(const uint4*)(kv8 + (size_t)csr_src[j + 0] * 1024 + (lane << 4));
    uint4 a1 = *(const uint4*)(kv8 + (size_t)csr_src[j + 1] * 1024 + (lane << 4));
    uint4 a2 = *(const uint4*)(kv8 + (size_t)csr_src[j + 2] * 1024 + (lane << 4));
    uint4 a3 = *(const uint4*)(kv8 + (size_t)csr_src[j + 3] * 1024 + (lane << 4));
    EDGE_A(a0)
    EDGE_A(a1)
    EDGE_A(a2)
    EDGE_A(a3)
  }
  for (; j < e1; ++j) {
    uint4 a0 = *(const uint4*)(kv8 + (size_t)csr_src[j] * 1024 + (lane << 4));
    EDGE_A(a0)
  }

  float dAll = kl ? den : 0.f;
  float dv = __shfl_xor(dAll, 32);
  if (!kl) {
    float inv = 1.f / fmaxf(dv, 1e-16f);
    int c0 = vl << 4;
    float sk[16];
    uint4 s0 = *(const uint4*)(h1b + (size_t)n * 512 + c0);
    uint4 s1 = *(const uint4*)(h1b + (size_t)n * 512 + c0 + 8);
    unpack8(s0, sk); unpack8(s1, sk + 8);
    ushort o[16];
    #pragma unroll
    for (int i = 0; i < 16; ++i)
      o[i] = f2bf(fmaxf(sk[i] + acc[i] * inv, 0.f));
    uint4 w0, w1;
    w0.x = (uint)o[0]  | ((uint)o[1]  << 16);
    w0.y = (uint)o[2]  | ((uint)o[3]  << 16);
    w0.z = (uint)o[4]  | ((uint)o[5]  << 16);
    w0.w = (uint)o[6]  | ((uint)o[7]  << 16);
    w1.x = (uint)o[8]  | ((uint)o[9]  << 16);
    w1.y = (uint)o[10] | ((uint)o[11] << 16);
    w1.z = (uint)o[12] | ((uint)o[13] << 16);
    w1.w = (uint)o[14] | ((uint)o[15] << 16);
    *(uint4*)(h1b + (size_t)n * 512 + c0) = w0;
    *(uint4*)(h1b + (size_t)n * 512 + c0 + 8) = w1;
  }
}

// ---- K5: layer-2 projections (bf16 h1, wave-uniform W loads) ---------------
__global__ __launch_bounds__(256) void gemm_l2(
    const ushort* __restrict__ h1b,
    const float* __restrict__ Wq, const float* __restrict__ bq,
    const float* __restrict__ Wk, const float* __restrict__ bk,
    const float* __restrict__ Wv, const float* __restrict__ bv,
    const float* __restrict__ Ws, const float* __restrict__ bs,
    float* __restrict__ qkv2, float* __restrict__ acc2)
{
  __shared__ float red[4][64][17];
  int n0 = blockIdx.x * 64;
  int wid = threadIdx.x >> 6, lane = threadIdx.x & 63;
  int n = n0 + lane;
  const float* Wm[4] = {Wq, Wk, Wv, Ws};
  float s[16] = {};
  if (n < NN) {
    const ushort* a = h1b + (size_t)n * 512 + wid * 128;
    #pragma unroll 2
    for (int i = 0; i < 128; i += 8) {
      uint4 hv = *(const uint4*)(a + i);
      float av[8]; unpack8(hv, av);
      #pragma unroll
      for (int j = 0; j < 16; ++j) {
        const float* w = Wm[j >> 2] + (size_t)(j & 3) * 512 + wid * 128 + i;
        s[j] += av[0]*w[0] + av[1]*w[1] + av[2]*w[2] + av[3]*w[3]
              + av[4]*w[4] + av[5]*w[5] + av[6]*w[6] + av[7]*w[7];
      }
    }
  }
  #pragma unroll
  for (int j = 0; j < 16; ++j) red[wid][lane][j] = s[j];
  __syncthreads();
  #pragma unroll
  for (int q = 0; q < 4; ++q) {
    int idx = threadIdx.x * 4 + q;
    int ln = idx >> 4, j = idx & 15;
    int nn2 = n0 + ln;
    if (nn2 >= NN) continue;
    float v = red[0][ln][j] + red[1][ln][j] + red[2][ln][j] + red[3][ln][j];
    int sg = j >> 2, r = j & 3;
    const float* bb = (sg == 0) ? bq : (sg == 1) ? bk : (sg == 2) ? bv : bs;
    v += bb[r];
    if (sg < 3) qkv2[nn2 * 12 + sg * 4 + r] = v;
    else        acc2[nn2 * 4 + r] = v;
  }
}

// ---- K6: layer-2 attention + skip + Wl dot + mean, fused -------------------
__global__ __launch_bounds__(256) void attn2_final(
    const float* __restrict__ qkv2, const int* __restrict__ rowptr,
    const int* __restrict__ csr_src, const float* __restrict__ acc2,
    const float* __restrict__ Wl, const float* __restrict__ bl,
    float* __restrict__ out)
{
  __shared__ float red[4];
  int t = blockIdx.x * 256 + threadIdx.x;   // grid covers NN*16 exactly
  int n = t >> 4, h = (t >> 2) & 3, part = t & 3;
  float q = qkv2[n * 12 + h];
  float den = 0.f, acc = 0.f;
  int e1 = rowptr[n + 1];
  for (int j = rowptr[n] + part; j < e1; j += 4) {
    int s = csr_src[j];
    float k = qkv2[s * 12 + 4 + h];
    float v = qkv2[s * 12 + 8 + h];
    float ex = __expf(q * k);
    den += ex; acc += ex * v;
  }
  den += __shfl_xor(den, 1); acc += __shfl_xor(acc, 1);
  den += __shfl_xor(den, 2); acc += __shfl_xor(acc, 2);
  float c = 0.f;
  if (part == 0)
    c = (acc2[n * 4 + h] + acc / fmaxf(den, 1e-16f)) * Wl[h] * (1.0f / NN);
  if (t == 0) c += bl[0];
  c += __shfl_xor(c, 4);
  c += __shfl_xor(c, 8);
  c += __shfl_xor(c, 16);
  c += __shfl_xor(c, 32);
  if ((threadIdx.x & 63) == 0) red[threadIdx.x >> 6] = c;
  __syncthreads();
  if (threadIdx.x == 0)
    unsafeAtomicAdd(out, red[0] + red[1] + red[2] + red[3]);
}

extern "C" void kernel_launch(void* const* d_in, const int* in_sizes, int n_in,
                              void* d_out, int out_size, void* d_ws, size_t ws_size,
                              hipStream_t stream)
{
  const float* x   = (const float*)d_in[0];
  const int*   ei  = (const int*)d_in[1];
  const float *Wq1 = (const float*)d_in[2],  *bq1 = (const float*)d_in[3];
  const float *Wk1 = (const float*)d_in[4],  *bk1 = (const float*)d_in[5];
  const float *Wv1 = (const float*)d_in[6],  *bv1 = (const float*)d_in[7];
  const float *Ws1 = (const float*)d_in[8],  *bs1 = (const float*)d_in[9];
  const float *Wq2 = (const float*)d_in[10], *bq2 = (const float*)d_in[11];
  const float *Wk2 = (const float*)d_in[12], *bk2 = (const float*)d_in[13];
  const float *Wv2 = (const float*)d_in[14], *bv2 = (const float*)d_in[15];
  const float *Ws2 = (const float*)d_in[16], *bs2 = (const float*)d_in[17];
  const float *Wl  = (const float*)d_in[18], *bl  = (const float*)d_in[19];
  const int* srcp = ei;
  const int* dstp = ei + NE;

  unsigned char* q8  = (unsigned char*)d_ws;           // NN*512 B
  unsigned char* kv8 = q8 + (size_t)NN * 512;          // NN*1024 B (k|v)
  ushort* x_bf = (ushort*)(kv8 + (size_t)NN * 1024);   // NN*128 bf16
  ushort* w1bf = x_bf + (size_t)NN * 128;              // 2048*128 bf16
  ushort* h1b  = w1bf + (size_t)2048 * 128;            // NN*512 bf16
  float*  qkv2 = (float*)(h1b + (size_t)NN * 512);     // NN*12
  float*  acc2 = qkv2 + (size_t)NN * 12;               // NN*4
  int*   deg     = (int*)(acc2 + (size_t)NN * 4);      // NN
  int*   rowptr  = deg + NN;                           // NN+1
  int*   cursor  = rowptr + NN + 1;                    // NN
  int*   csr_src = cursor + NN;                        // NE

  zero_k<<<10, 1024, 0, stream>>>(deg, (float*)d_out);
  {
    const int total = NN * 32 + 4 * (512 * 128 / 4);
    prep_k<<<(total + 255) / 256, 256, 0, stream>>>(
        x, Wq1, Wk1, Wv1, Ws1, x_bf, w1bf, dstp, deg);
  }
  scan_k<<<1, 1024, 0, stream>>>(deg, rowptr, cursor);

  gemm_scatter<<<NGEMM + (NE + 255) / 256, 256, 0, stream>>>(
      x_bf, w1bf, bq1, bk1, bv1, bs1, q8, kv8, h1b,
      srcp, dstp, cursor, csr_src);

  attn1<<<NN / 4, 256, 0, stream>>>(q8, kv8, rowptr, csr_src, h1b);

  gemm_l2<<<(NN + 63) / 64, 256, 0, stream>>>(
      h1b, Wq2, bq2, Wk2, bk2, Wv2, bv2, Ws2, bs2, qkv2, acc2);

  attn2_final<<<NN * 16 / 256, 256, 0, stream>>>(
      qkv2, rowptr, csr_src, acc2, Wl, bl, (float*)d_out);
}